// Round 7
// baseline (20.162 us; speedup 1.0000x reference)
//
#include <hip/hip_runtime.h>
#include <math.h>

// Problem constants: B=2, M=N=8192, K=32, C=16, O=16, ncells=27
#define NP 8192
#define KN 32
#define CH 16
#define OCH 16
#define NCELL 27
#define EPAD 36   // row stride: 27 real + 9 zeros; c*36%32 = c*4 -> <=2-way banks

// exact cull bound: (0.1 + 0.05*sqrt(3))^2 = 0.0348205; 0.0349 safely inclusive
#define THR2 0.0349f

__device__ __forceinline__ float rlf(float x, int l) {
    return __int_as_float(__builtin_amdgcn_readlane(__float_as_int(x), l));
}
// VALU cross-lane: DPP quad_perm / row_ror (no DS pipe, no lgkmcnt)
__device__ __forceinline__ float dpp_xor1(float x) {   // lane ^ 1
    return __int_as_float(__builtin_amdgcn_mov_dpp(__float_as_int(x), 0xB1, 0xF, 0xF, true));
}
__device__ __forceinline__ float dpp_xor2(float x) {   // lane ^ 2
    return __int_as_float(__builtin_amdgcn_mov_dpp(__float_as_int(x), 0x4E, 0xF, 0xF, true));
}
__device__ __forceinline__ float dpp_xor8(float x) {   // lane ^ 8 (row_ror:8)
    return __int_as_float(__builtin_amdgcn_mov_dpp(__float_as_int(x), 0x128, 0xF, 0xF, true));
}
// x + x[lane^16] / x + x[lane^32] via gfx950 permlane swaps (VALU):
__device__ __forceinline__ float fold16(float x) {
#if __has_builtin(__builtin_amdgcn_permlane16_swap)
    typedef unsigned uv2 __attribute__((ext_vector_type(2)));
    uv2 rr = __builtin_amdgcn_permlane16_swap(__float_as_uint(x), __float_as_uint(x), false, false);
    return __uint_as_float(rr[0]) + __uint_as_float(rr[1]);
#else
    return x + __shfl_xor(x, 16, 64);
#endif
}
__device__ __forceinline__ float fold32(float x) {
#if __has_builtin(__builtin_amdgcn_permlane32_swap)
    typedef unsigned uv2 __attribute__((ext_vector_type(2)));
    uv2 rr = __builtin_amdgcn_permlane32_swap(__float_as_uint(x), __float_as_uint(x), false, false);
    return __uint_as_float(rr[0]) + __uint_as_float(rr[1]);
#else
    return x + __shfl_xor(x, 32, 64);
#endif
}

__global__ __launch_bounds__(512, 4) void convsp_kernel(
    const float* __restrict__ qlocs,
    const float* __restrict__ locs,
    const float* __restrict__ data,
    const int*   __restrict__ neighbors,
    const float* __restrict__ weight,
    const float* __restrict__ bias,
    float* __restrict__ out)
{
    __shared__ float wlds[OCH * CH * EPAD];   // 36864 B

    const int tid  = threadIdx.x;
    const int lane = tid & 63;
    const int c    = lane & 15;        // channel
    const int h    = lane >> 4;        // 0..3: e-slice AND this lane's cull-point
    const int wv   = tid >> 6;         // wave id in block
    const int pt0  = blockIdx.x * 32 + wv * 4;   // wave owns points pt0..pt0+3
    const int b    = blockIdx.x >> 8;  // 512 blocks, 256 per batch
    const int bN   = b * NP;

    // ---- issue-early: weight loads into registers ----
    const float4* w4g = (const float4*)weight;   // 6912 floats = 1728 float4
    float4 wr0 = w4g[tid];
    float4 wr1 = w4g[tid + 512];
    float4 wr2 = w4g[tid + 1024];
    float4 wr3 = (tid < 192) ? w4g[tid + 1536] : make_float4(0.f, 0.f, 0.f, 0.f);

    // own cull point (p == h): query coords + two neighbor slots (k=c, k=c+16)
    const int ptq = pt0 + h;
    const float qx = qlocs[ptq * 3 + 0];
    const float qy = qlocs[ptq * 3 + 1];
    const float qz = qlocs[ptq * 3 + 2];
    const float bi = bias[c];
    const int nid0 = neighbors[ptq * KN + c];
    const int nid1 = neighbors[ptq * KN + 16 + c];
    int g0 = (bN + max(nid0, 0)) * 3;
    int g1 = (bN + max(nid1, 0)) * 3;
    float l0x = locs[g0], l0y = locs[g0 + 1], l0z = locs[g0 + 2];
    float l1x = locs[g1], l1y = locs[g1 + 1], l1z = locs[g1 + 2];

    // ---- zero-fill pad columns e=27..35 ----
    for (int idx = tid; idx < OCH * CH * 9; idx += 512) {
        int row = idx / 9;
        wlds[row * EPAD + 27 + (idx - row * 9)] = 0.0f;
    }

    // ---- cull: lane evaluates its 2 slots for point h (hides weight vmcnt) ----
    float dx0 = qx - l0x, dy0 = qy - l0y, dz0 = qz - l0z;
    float dx1 = qx - l1x, dy1 = qy - l1y, dz1 = qz - l1z;
    bool hit0 = (nid0 >= 0) && (dx0 * dx0 + dy0 * dy0 + dz0 * dz0 < THR2);
    bool hit1 = (nid1 >= 0) && (dx1 * dx1 + dy1 * dy1 + dz1 * dz1 < THR2);
    unsigned long long bl0 = __ballot(hit0);   // bits p*16+j : point p, slot j
    unsigned long long bl1 = __ballot(hit1);   // bits p*16+j : point p, slot 16+j

    // wave-uniform per-point masks (ballot-derived -> SGPR, scalar branches)
    unsigned int mk[4];
    #pragma unroll
    for (int p = 0; p < 4; ++p)
        mk[p] = (unsigned int)((bl0 >> (p * 16)) & 0xFFFFull)
              | ((unsigned int)((bl1 >> (p * 16)) & 0xFFFFull) << 16);

    // ---- stage weights to LDS, then ONE uniform barrier (before hit loops:
    //      no straggler wave can stall the block) ----
    #pragma unroll
    for (int j = 0; j < 4; ++j) {
        if (j < 3 || tid < 192) {
            float4 w = (j == 0) ? wr0 : (j == 1) ? wr1 : (j == 2) ? wr2 : wr3;
            int f  = (tid + j * 512) * 4;
            int r0 = (f + 0) / NCELL, e0 = (f + 0) - r0 * NCELL;
            int r1 = (f + 1) / NCELL, e1 = (f + 1) - r1 * NCELL;
            int r2 = (f + 2) / NCELL, e2 = (f + 2) - r2 * NCELL;
            int r3 = (f + 3) / NCELL, e3 = (f + 3) - r3 * NCELL;
            wlds[r0 * EPAD + e0] = w.x;
            wlds[r1 * EPAD + e1] = w.y;
            wlds[r2 * EPAD + e2] = w.z;
            wlds[r3 * EPAD + e3] = w.w;
        }
    }
    __syncthreads();

    // ---- this lane's 8 cell offsets (arithmetic, register-resident) ----
    float oxr[8], oyr[8], ozr[8];
    #pragma unroll
    for (int i = 0; i < 8; ++i) {
        int e  = h * 8 + i;               // 0..31
        int d9 = (e * 228) >> 11;         // e/9  (valid e<32)
        int d3 = (e * 683) >> 11;         // e/3  (valid e<32)
        oxr[i] = (float)(d9 - 1) * 0.05f;
        oyr[i] = (float)(d3 - 3 * d9 - 1) * 0.05f;
        ozr[i] = (float)(e - 3 * d3 - 1) * 0.05f;
    }

    float acc[4][8];
    #pragma unroll
    for (int p = 0; p < 4; ++p)
        #pragma unroll
        for (int i = 0; i < 8; ++i) acc[p][i] = 0.0f;

    // ---- per-point hit loops: scalar control, readlane broadcast,
    //      1-deep pipelined data gather ----
    #pragma unroll
    for (int p = 0; p < 4; ++p) {
        unsigned int mp = mk[p];

        auto FETCH = [&](int k, int& nk, float& ax, float& ay, float& az) {
            int src = p * 16 + (k & 15);
            if (k < 16) {
                nk = __builtin_amdgcn_readlane(nid0, src);
                ax = rlf(dx0, src); ay = rlf(dy0, src); az = rlf(dz0, src);
            } else {
                nk = __builtin_amdgcn_readlane(nid1, src);
                ax = rlf(dx1, src); ay = rlf(dy1, src); az = rlf(dz1, src);
            }
        };
        auto ACCUM = [&](float (&a)[8], float dqx, float dqy, float dqz, float ndc) {
            #pragma unroll
            for (int i = 0; i < 8; ++i) {
                float ex = dqx + oxr[i], ey = dqy + oyr[i], ez = dqz + ozr[i];
                float t  = fmaf(ex, ex, fmaf(ey, ey, ez * ez)) + 1e-12f;
                float u  = fmaxf(fmaf(-10.0f, __builtin_amdgcn_sqrtf(t), 1.0f), 0.0f);
                a[i] += (u * u) * (u * ndc);
            }
        };

        if (mp) {
            int k = __builtin_ctz(mp); mp &= mp - 1;
            int nk; float dqx, dqy, dqz;
            FETCH(k, nk, dqx, dqy, dqz);
            float ndc = data[(bN + nk) * CH + c];
            while (mp) {
                int k2 = __builtin_ctz(mp); mp &= mp - 1;
                int nk2; float dqx2, dqy2, dqz2;
                FETCH(k2, nk2, dqx2, dqy2, dqz2);
                float ndc2 = data[(bN + nk2) * CH + c];   // in flight during ACCUM
                ACCUM(acc[p], dqx, dqy, dqz, ndc);
                dqx = dqx2; dqy = dqy2; dqz = dqz2; ndc = ndc2;
            }
            ACCUM(acc[p], dqx, dqy, dqz, ndc);
        }
    }

    // ---- contraction: weight reads shared across the wave's 4 points;
    //      per-point scalar-branch skip (41% of points are zero-hit);
    //      split dot chains; butterfly on VALU except xor4 ----
    float vv[4][8];
    const float* wrow = &wlds[c * EPAD + h * 8];
    const int bit0 = c & 1;
    #pragma unroll
    for (int j = 0; j < 8; ++j) {
        const float4* wA = (const float4*)(wrow + (2 * j)     * CH * EPAD);
        const float4* wB = (const float4*)(wrow + (2 * j + 1) * CH * EPAD);
        float4 a0 = wA[0], a1 = wA[1];
        float4 b0 = wB[0], b1 = wB[1];
        #pragma unroll
        for (int p = 0; p < 4; ++p) {
            if (mk[p]) {   // wave-uniform -> s_cbranch
                float pA = (a0.x*acc[p][0] + a0.y*acc[p][1] + a0.z*acc[p][2] + a0.w*acc[p][3])
                         + (a1.x*acc[p][4] + a1.y*acc[p][5] + a1.z*acc[p][6] + a1.w*acc[p][7]);
                float pB = (b0.x*acc[p][0] + b0.y*acc[p][1] + b0.z*acc[p][2] + b0.w*acc[p][3])
                         + (b1.x*acc[p][4] + b1.y*acc[p][5] + b1.z*acc[p][6] + b1.w*acc[p][7]);
                float keep = bit0 ? pB : pA;
                float send = bit0 ? pA : pB;
                vv[p][j] = keep + dpp_xor1(send);
            }
        }
    }

    float rps[4];
    #pragma unroll
    for (int p = 0; p < 4; ++p) {
        rps[p] = 0.0f;
        if (mk[p]) {
            // stage 1: xor2 (DPP)
            {
                const int bit = (c >> 1) & 1;
                #pragma unroll
                for (int j = 0; j < 4; ++j) {
                    float keep = bit ? vv[p][2 * j + 1] : vv[p][2 * j];
                    float send = bit ? vv[p][2 * j]     : vv[p][2 * j + 1];
                    vv[p][j] = keep + dpp_xor2(send);
                }
            }
            // stage 2: xor4 (DS swizzle — no DPP pattern for lane^4)
            {
                const int bit = (c >> 2) & 1;
                #pragma unroll
                for (int j = 0; j < 2; ++j) {
                    float keep = bit ? vv[p][2 * j + 1] : vv[p][2 * j];
                    float send = bit ? vv[p][2 * j]     : vv[p][2 * j + 1];
                    vv[p][j] = keep + __shfl_xor(send, 4, 64);
                }
            }
            // stage 3: xor8 (DPP row_ror:8)
            {
                const int bit = (c >> 3) & 1;
                float keep = bit ? vv[p][1] : vv[p][0];
                float send = bit ? vv[p][0] : vv[p][1];
                vv[p][0] = keep + dpp_xor8(send);
            }
            // merge the 4 e-slices: xor16, xor32 on VALU
            rps[p] = fold32(fold16(vv[p][0]));
        }
    }

    // lane (c,h) writes point pt0+h, channel o=c -> out[pt0*16 + lane], 256B coalesced
    float rw = rps[0];
    if (h == 1) rw = rps[1];
    if (h == 2) rw = rps[2];
    if (h == 3) rw = rps[3];
    out[pt0 * CH + lane] = rw + bi;
}

extern "C" void kernel_launch(void* const* d_in, const int* in_sizes, int n_in,
                              void* d_out, int out_size, void* d_ws, size_t ws_size,
                              hipStream_t stream) {
    const float* qlocs     = (const float*)d_in[0];
    const float* locs      = (const float*)d_in[1];
    const float* data      = (const float*)d_in[2];
    const int*   neighbors = (const int*)d_in[3];
    const float* weight    = (const float*)d_in[4];
    const float* bias      = (const float*)d_in[5];
    float*       out       = (float*)d_out;

    const int BM = in_sizes[0] / 3;   // B*M = 16384
    dim3 grid(BM / 32), block(512);
    hipLaunchKernelGGL(convsp_kernel, grid, block, 0, stream,
                       qlocs, locs, data, neighbors, weight, bias, out);
}

// Round 8
// 18.414 us; speedup vs baseline: 1.0949x; 1.0949x over previous
//
#include <hip/hip_runtime.h>
#include <math.h>

// Problem constants: B=2, M=N=8192, K=32, C=16, O=16, ncells=27
#define NP 8192
#define KN 32
#define CH 16
#define OCH 16
#define NCELL 27
#define EPAD 36   // row stride: 27 real + 9 zeros; c*36%32 = c*4 -> <=2-way banks

// exact cull bound: (0.1 + 0.05*sqrt(3))^2 = 0.0348205; 0.0349 safely inclusive
#define THR2 0.0349f

__device__ __forceinline__ float rlf(float x, int l) {
    return __int_as_float(__builtin_amdgcn_readlane(__float_as_int(x), l));
}
// VALU cross-lane: DPP quad_perm / row_ror (no DS pipe, no lgkmcnt)
__device__ __forceinline__ float dpp_xor1(float x) {   // lane ^ 1
    return __int_as_float(__builtin_amdgcn_mov_dpp(__float_as_int(x), 0xB1, 0xF, 0xF, true));
}
__device__ __forceinline__ float dpp_xor2(float x) {   // lane ^ 2
    return __int_as_float(__builtin_amdgcn_mov_dpp(__float_as_int(x), 0x4E, 0xF, 0xF, true));
}
__device__ __forceinline__ float dpp_xor8(float x) {   // lane ^ 8 (row_ror:8)
    return __int_as_float(__builtin_amdgcn_mov_dpp(__float_as_int(x), 0x128, 0xF, 0xF, true));
}
// x + x[lane^16] / x + x[lane^32] via gfx950 permlane swaps (VALU):
__device__ __forceinline__ float fold16(float x) {
#if __has_builtin(__builtin_amdgcn_permlane16_swap)
    typedef unsigned uv2 __attribute__((ext_vector_type(2)));
    uv2 rr = __builtin_amdgcn_permlane16_swap(__float_as_uint(x), __float_as_uint(x), false, false);
    return __uint_as_float(rr[0]) + __uint_as_float(rr[1]);
#else
    return x + __shfl_xor(x, 16, 64);
#endif
}
__device__ __forceinline__ float fold32(float x) {
#if __has_builtin(__builtin_amdgcn_permlane32_swap)
    typedef unsigned uv2 __attribute__((ext_vector_type(2)));
    uv2 rr = __builtin_amdgcn_permlane32_swap(__float_as_uint(x), __float_as_uint(x), false, false);
    return __uint_as_float(rr[0]) + __uint_as_float(rr[1]);
#else
    return x + __shfl_xor(x, 32, 64);
#endif
}

__global__ __launch_bounds__(512, 4) void convsp_kernel(
    const float* __restrict__ qlocs,
    const float* __restrict__ locs,
    const float* __restrict__ data,
    const int*   __restrict__ neighbors,
    const float* __restrict__ weight,
    const float* __restrict__ bias,
    float* __restrict__ out)
{
    __shared__ float wlds[OCH * CH * EPAD];   // 36864 B

    const int tid  = threadIdx.x;
    const int lane = tid & 63;
    const int c    = lane & 15;        // channel
    const int h    = lane >> 4;        // 0..3: e-slice AND this lane's cull-point
    const int wv   = tid >> 6;         // wave id in block
    const int pt0  = blockIdx.x * 32 + wv * 4;   // wave owns points pt0..pt0+3
    const int b    = blockIdx.x >> 8;  // 512 blocks, 256 per batch
    const int bN   = b * NP;

    // ---- T14 issue-early: weight loads into registers (write to LDS later) ----
    const float4* w4g = (const float4*)weight;   // 6912 floats = 1728 float4
    float4 wr0 = w4g[tid];
    float4 wr1 = w4g[tid + 512];
    float4 wr2 = w4g[tid + 1024];
    float4 wr3 = (tid < 192) ? w4g[tid + 1536] : make_float4(0.f, 0.f, 0.f, 0.f);

    // own cull point (p == h): query coords + two neighbor slots (k=c, k=c+16)
    const int ptq = pt0 + h;
    const float qx = qlocs[ptq * 3 + 0];
    const float qy = qlocs[ptq * 3 + 1];
    const float qz = qlocs[ptq * 3 + 2];
    const float bi = bias[c];
    const int nid0 = neighbors[ptq * KN + c];
    const int nid1 = neighbors[ptq * KN + 16 + c];
    int g0 = (bN + max(nid0, 0)) * 3;
    int g1 = (bN + max(nid1, 0)) * 3;
    float l0x = locs[g0], l0y = locs[g0 + 1], l0z = locs[g0 + 2];
    float l1x = locs[g1], l1y = locs[g1 + 1], l1z = locs[g1 + 2];

    // ---- zero-fill pad columns e=27..35 ----
    for (int idx = tid; idx < OCH * CH * 9; idx += 512) {
        int row = idx / 9;
        wlds[row * EPAD + 27 + (idx - row * 9)] = 0.0f;
    }

    // ---- this lane's 8 cell offsets (arithmetic, register-resident) ----
    float oxr[8], oyr[8], ozr[8];
    #pragma unroll
    for (int i = 0; i < 8; ++i) {
        int e  = h * 8 + i;               // 0..31
        int d9 = (e * 228) >> 11;         // e/9  (valid e<32)
        int d3 = (e * 683) >> 11;         // e/3  (valid e<32)
        oxr[i] = (float)(d9 - 1) * 0.05f;
        oyr[i] = (float)(d3 - 3 * d9 - 1) * 0.05f;
        ozr[i] = (float)(e - 3 * d3 - 1) * 0.05f;
    }

    // ---- cull: lane evaluates its 2 slots for point h ----
    float dx0 = qx - l0x, dy0 = qy - l0y, dz0 = qz - l0z;
    float dx1 = qx - l1x, dy1 = qy - l1y, dz1 = qz - l1z;
    bool hit0 = (nid0 >= 0) && (dx0 * dx0 + dy0 * dy0 + dz0 * dz0 < THR2);
    bool hit1 = (nid1 >= 0) && (dx1 * dx1 + dy1 * dy1 + dz1 * dz1 < THR2);
    unsigned long long bl0 = __ballot(hit0);   // bits p*16+j : point p, slot j
    unsigned long long bl1 = __ballot(hit1);   // bits p*16+j : point p, slot 16+j

    // wave-uniform per-point masks (SGPR-resident)
    unsigned int mk[4];
    #pragma unroll
    for (int p = 0; p < 4; ++p)
        mk[p] = (unsigned int)((bl0 >> (p * 16)) & 0xFFFFull)
              | ((unsigned int)((bl1 >> (p * 16)) & 0xFFFFull) << 16);

    float acc[4][8];
    #pragma unroll
    for (int p = 0; p < 4; ++p)
        #pragma unroll
        for (int i = 0; i < 8; ++i) acc[p][i] = 0.0f;

    auto FETCH = [&](int p, int k, int& nk, float& ax, float& ay, float& az) {
        int src = p * 16 + (k & 15);
        if (k < 16) {
            nk = __builtin_amdgcn_readlane(nid0, src);
            ax = rlf(dx0, src); ay = rlf(dy0, src); az = rlf(dz0, src);
        } else {
            nk = __builtin_amdgcn_readlane(nid1, src);
            ax = rlf(dx1, src); ay = rlf(dy1, src); az = rlf(dz1, src);
        }
    };
    auto ACCUM = [&](float (&a)[8], float dqx, float dqy, float dqz, float ndc) {
        #pragma unroll
        for (int i = 0; i < 8; ++i) {
            float ex = dqx + oxr[i], ey = dqy + oyr[i], ez = dqz + ozr[i];
            float t  = fmaf(ex, ex, fmaf(ey, ey, ez * ez)) + 1e-12f;
            float u  = fmaxf(fmaf(-10.0f, __builtin_amdgcn_sqrtf(t), 1.0f), 0.0f);
            a[i] += (u * u) * (u * ndc);
        }
    };

    // ---- Phase A: peel first hit of EVERY point, issue the 4 data gathers
    //      back-to-back so their latencies overlap (previously serialized) ----
    float p1x[4], p1y[4], p1z[4], nd1[4];
    unsigned int rest[4];
    #pragma unroll
    for (int p = 0; p < 4; ++p) {
        unsigned int mp = mk[p];
        rest[p] = 0;
        if (mp) {
            int k = __builtin_ctz(mp);
            rest[p] = mp & (mp - 1);
            int nk;
            FETCH(p, k, nk, p1x[p], p1y[p], p1z[p]);
            nd1[p] = data[(bN + nk) * CH + c];      // 4 gathers in flight together
        }
    }

    // ---- Phase B: per-point processing; 1-deep pipe within multi-hit points ----
    #pragma unroll
    for (int p = 0; p < 4; ++p) {
        if (mk[p]) {
            float dqx = p1x[p], dqy = p1y[p], dqz = p1z[p], ndc = nd1[p];
            unsigned int mp = rest[p];
            while (mp) {
                int k2 = __builtin_ctz(mp); mp &= mp - 1;
                int nk2; float dqx2, dqy2, dqz2;
                FETCH(p, k2, nk2, dqx2, dqy2, dqz2);
                float ndc2 = data[(bN + nk2) * CH + c];   // in flight during ACCUM
                ACCUM(acc[p], dqx, dqy, dqz, ndc);
                dqx = dqx2; dqy = dqy2; dqz = dqz2; ndc = ndc2;
            }
            ACCUM(acc[p], dqx, dqy, dqz, ndc);
        }
    }

    // ---- T14 write-late: stage weights to LDS (padded rows), then barrier ----
    #pragma unroll
    for (int j = 0; j < 4; ++j) {
        if (j < 3 || tid < 192) {
            float4 w = (j == 0) ? wr0 : (j == 1) ? wr1 : (j == 2) ? wr2 : wr3;
            int f  = (tid + j * 512) * 4;
            int r0 = (f + 0) / NCELL, e0 = (f + 0) - r0 * NCELL;
            int r1 = (f + 1) / NCELL, e1 = (f + 1) - r1 * NCELL;
            int r2 = (f + 2) / NCELL, e2 = (f + 2) - r2 * NCELL;
            int r3 = (f + 3) / NCELL, e3 = (f + 3) - r3 * NCELL;
            wlds[r0 * EPAD + e0] = w.x;
            wlds[r1 * EPAD + e1] = w.y;
            wlds[r2 * EPAD + e2] = w.z;
            wlds[r3 * EPAD + e3] = w.w;
        }
    }
    __syncthreads();

    // ---- contraction: weight reads shared across the wave's 4 points;
    //      split dot chains (2x ILP); butterfly on VALU except xor4 ----
    float r0s = 0.f, r1s = 0.f, r2s = 0.f, r3s = 0.f;
    if (bl0 | bl1) {
        const float* wrow = &wlds[c * EPAD + h * 8];
        const int bit0 = c & 1;
        float vv[4][8];
        #pragma unroll
        for (int j = 0; j < 8; ++j) {
            const float4* wA = (const float4*)(wrow + (2 * j)     * CH * EPAD);
            const float4* wB = (const float4*)(wrow + (2 * j + 1) * CH * EPAD);
            float4 a0 = wA[0], a1 = wA[1];
            float4 b0 = wB[0], b1 = wB[1];
            #pragma unroll
            for (int p = 0; p < 4; ++p) {
                float pA = (a0.x*acc[p][0] + a0.y*acc[p][1] + a0.z*acc[p][2] + a0.w*acc[p][3])
                         + (a1.x*acc[p][4] + a1.y*acc[p][5] + a1.z*acc[p][6] + a1.w*acc[p][7]);
                float pB = (b0.x*acc[p][0] + b0.y*acc[p][1] + b0.z*acc[p][2] + b0.w*acc[p][3])
                         + (b1.x*acc[p][4] + b1.y*acc[p][5] + b1.z*acc[p][6] + b1.w*acc[p][7]);
                float keep = bit0 ? pB : pA;
                float send = bit0 ? pA : pB;
                vv[p][j] = keep + dpp_xor1(send);
            }
        }
        // stage 1: xor2 (DPP)
        {
            const int bit = (c >> 1) & 1;
            #pragma unroll
            for (int p = 0; p < 4; ++p)
                #pragma unroll
                for (int j = 0; j < 4; ++j) {
                    float keep = bit ? vv[p][2 * j + 1] : vv[p][2 * j];
                    float send = bit ? vv[p][2 * j]     : vv[p][2 * j + 1];
                    vv[p][j] = keep + dpp_xor2(send);
                }
        }
        // stage 2: xor4 (DS swizzle — no DPP pattern for lane^4)
        {
            const int bit = (c >> 2) & 1;
            #pragma unroll
            for (int p = 0; p < 4; ++p)
                #pragma unroll
                for (int j = 0; j < 2; ++j) {
                    float keep = bit ? vv[p][2 * j + 1] : vv[p][2 * j];
                    float send = bit ? vv[p][2 * j]     : vv[p][2 * j + 1];
                    vv[p][j] = keep + __shfl_xor(send, 4, 64);
                }
        }
        // stage 3: xor8 (DPP row_ror:8)
        {
            const int bit = (c >> 3) & 1;
            #pragma unroll
            for (int p = 0; p < 4; ++p) {
                float keep = bit ? vv[p][1] : vv[p][0];
                float send = bit ? vv[p][0] : vv[p][1];
                vv[p][0] = keep + dpp_xor8(send);
            }
        }
        // merge the 4 e-slices (h groups) per point: xor16, xor32 on VALU
        r0s = fold32(fold16(vv[0][0]));
        r1s = fold32(fold16(vv[1][0]));
        r2s = fold32(fold16(vv[2][0]));
        r3s = fold32(fold16(vv[3][0]));
    }

    // lane (c,h) writes point pt0+h, channel o=c -> out[pt0*16 + lane], 256B coalesced
    float rw = r0s;
    if (h == 1) rw = r1s;
    if (h == 2) rw = r2s;
    if (h == 3) rw = r3s;
    out[pt0 * CH + lane] = rw + bi;
}

extern "C" void kernel_launch(void* const* d_in, const int* in_sizes, int n_in,
                              void* d_out, int out_size, void* d_ws, size_t ws_size,
                              hipStream_t stream) {
    const float* qlocs     = (const float*)d_in[0];
    const float* locs      = (const float*)d_in[1];
    const float* data      = (const float*)d_in[2];
    const int*   neighbors = (const int*)d_in[3];
    const float* weight    = (const float*)d_in[4];
    const float* bias      = (const float*)d_in[5];
    float*       out       = (float*)d_out;

    const int BM = in_sizes[0] / 3;   // B*M = 16384
    dim3 grid(BM / 32), block(512);
    hipLaunchKernelGGL(convsp_kernel, grid, block, 0, stream,
                       qlocs, locs, data, neighbors, weight, bias, out);
}

// Round 9
// 17.894 us; speedup vs baseline: 1.1268x; 1.0291x over previous
//
#include <hip/hip_runtime.h>
#include <math.h>

// Problem constants: B=2, M=N=8192, K=32, C=16, O=16, ncells=27
#define NP 8192
#define KN 32
#define CH 16
#define OCH 16
#define NCELL 27
#define EPAD 36   // row stride: 27 real + 9 zeros; c*36%32 = c*4 -> <=2-way banks

// exact cull bound: (0.1 + 0.05*sqrt(3))^2 = 0.0348205; 0.0349 safely inclusive
#define THR2 0.0349f

__device__ __forceinline__ float rlf(float x, int l) {
    return __int_as_float(__builtin_amdgcn_readlane(__float_as_int(x), l));
}
// VALU cross-lane: DPP quad_perm / row_ror (no DS pipe, no lgkmcnt)
__device__ __forceinline__ float dpp_xor1(float x) {   // lane ^ 1
    return __int_as_float(__builtin_amdgcn_mov_dpp(__float_as_int(x), 0xB1, 0xF, 0xF, true));
}
__device__ __forceinline__ float dpp_xor2(float x) {   // lane ^ 2
    return __int_as_float(__builtin_amdgcn_mov_dpp(__float_as_int(x), 0x4E, 0xF, 0xF, true));
}
__device__ __forceinline__ float dpp_xor8(float x) {   // lane ^ 8 (row_ror:8)
    return __int_as_float(__builtin_amdgcn_mov_dpp(__float_as_int(x), 0x128, 0xF, 0xF, true));
}
// x + x[lane^16] / x + x[lane^32] via gfx950 permlane swaps (VALU):
// with both operands = x, sum of the two outputs = x + partner on every lane.
__device__ __forceinline__ float fold16(float x) {
#if __has_builtin(__builtin_amdgcn_permlane16_swap)
    typedef unsigned uv2 __attribute__((ext_vector_type(2)));
    uv2 rr = __builtin_amdgcn_permlane16_swap(__float_as_uint(x), __float_as_uint(x), false, false);
    return __uint_as_float(rr[0]) + __uint_as_float(rr[1]);
#else
    return x + __shfl_xor(x, 16, 64);
#endif
}
__device__ __forceinline__ float fold32(float x) {
#if __has_builtin(__builtin_amdgcn_permlane32_swap)
    typedef unsigned uv2 __attribute__((ext_vector_type(2)));
    uv2 rr = __builtin_amdgcn_permlane32_swap(__float_as_uint(x), __float_as_uint(x), false, false);
    return __uint_as_float(rr[0]) + __uint_as_float(rr[1]);
#else
    return x + __shfl_xor(x, 32, 64);
#endif
}

__global__ __launch_bounds__(512, 4) void convsp_kernel(
    const float* __restrict__ qlocs,
    const float* __restrict__ locs,
    const float* __restrict__ data,
    const int*   __restrict__ neighbors,
    const float* __restrict__ weight,
    const float* __restrict__ bias,
    float* __restrict__ out)
{
    __shared__ float wlds[OCH * CH * EPAD];   // 36864 B

    const int tid  = threadIdx.x;
    const int lane = tid & 63;
    const int c    = lane & 15;        // channel
    const int h    = lane >> 4;        // 0..3: e-slice AND this lane's cull-point
    const int wv   = tid >> 6;         // wave id in block
    const int pt0  = blockIdx.x * 32 + wv * 4;   // wave owns points pt0..pt0+3
    const int b    = blockIdx.x >> 8;  // 512 blocks, 256 per batch
    const int bN   = b * NP;

    // ---- T14 issue-early: weight loads into registers (write to LDS later) ----
    const float4* w4g = (const float4*)weight;   // 6912 floats = 1728 float4
    float4 wr0 = w4g[tid];
    float4 wr1 = w4g[tid + 512];
    float4 wr2 = w4g[tid + 1024];
    float4 wr3 = (tid < 192) ? w4g[tid + 1536] : make_float4(0.f, 0.f, 0.f, 0.f);

    // own cull point (p == h): query coords + two neighbor slots (k=c, k=c+16)
    const int ptq = pt0 + h;
    const float qx = qlocs[ptq * 3 + 0];
    const float qy = qlocs[ptq * 3 + 1];
    const float qz = qlocs[ptq * 3 + 2];
    const float bi = bias[c];
    const int nid0 = neighbors[ptq * KN + c];
    const int nid1 = neighbors[ptq * KN + 16 + c];
    int g0 = (bN + max(nid0, 0)) * 3;
    int g1 = (bN + max(nid1, 0)) * 3;
    float l0x = locs[g0], l0y = locs[g0 + 1], l0z = locs[g0 + 2];
    float l1x = locs[g1], l1y = locs[g1 + 1], l1z = locs[g1 + 2];

    // ---- zero-fill pad columns e=27..35 ----
    for (int idx = tid; idx < OCH * CH * 9; idx += 512) {
        int row = idx / 9;
        wlds[row * EPAD + 27 + (idx - row * 9)] = 0.0f;
    }

    // ---- this lane's 8 cell offsets (arithmetic, no LDS table) ----
    float oxr[8], oyr[8], ozr[8];
    #pragma unroll
    for (int i = 0; i < 8; ++i) {
        int e  = h * 8 + i;               // 0..31
        int d9 = (e * 228) >> 11;         // e/9  (valid e<32)
        int d3 = (e * 683) >> 11;         // e/3  (valid e<32)
        oxr[i] = (float)(d9 - 1) * 0.05f;
        oyr[i] = (float)(d3 - 3 * d9 - 1) * 0.05f;
        ozr[i] = (float)(e - 3 * d3 - 1) * 0.05f;
    }

    // ---- cull: lane evaluates its 2 slots for point h ----
    float dx0 = qx - l0x, dy0 = qy - l0y, dz0 = qz - l0z;
    float dx1 = qx - l1x, dy1 = qy - l1y, dz1 = qz - l1z;
    bool hit0 = (nid0 >= 0) && (dx0 * dx0 + dy0 * dy0 + dz0 * dz0 < THR2);
    bool hit1 = (nid1 >= 0) && (dx1 * dx1 + dy1 * dy1 + dz1 * dz1 < THR2);
    unsigned long long bl0 = __ballot(hit0);   // bits p*16+j : point p, slot j
    unsigned long long bl1 = __ballot(hit1);   // bits p*16+j : point p, slot 16+j

    float acc[4][8];
    #pragma unroll
    for (int p = 0; p < 4; ++p)
        #pragma unroll
        for (int i = 0; i < 8; ++i) acc[p][i] = 0.0f;

    // ---- per-point hit loops: scalar control, readlane broadcast (no DS),
    //      1-deep pipelined data gather ----
    #pragma unroll
    for (int p = 0; p < 4; ++p) {
        unsigned int mp = (unsigned int)((bl0 >> (p * 16)) & 0xFFFFull)
                        | ((unsigned int)((bl1 >> (p * 16)) & 0xFFFFull) << 16);

        auto FETCH = [&](int k, int& nk, float& ax, float& ay, float& az) {
            int src = p * 16 + (k & 15);
            if (k < 16) {
                nk = __builtin_amdgcn_readlane(nid0, src);
                ax = rlf(dx0, src); ay = rlf(dy0, src); az = rlf(dz0, src);
            } else {
                nk = __builtin_amdgcn_readlane(nid1, src);
                ax = rlf(dx1, src); ay = rlf(dy1, src); az = rlf(dz1, src);
            }
        };
        auto ACCUM = [&](float (&a)[8], float dqx, float dqy, float dqz, float ndc) {
            #pragma unroll
            for (int i = 0; i < 8; ++i) {
                float ex = dqx + oxr[i], ey = dqy + oyr[i], ez = dqz + ozr[i];
                float t  = fmaf(ex, ex, fmaf(ey, ey, ez * ez)) + 1e-12f;
                float u  = fmaxf(fmaf(-10.0f, __builtin_amdgcn_sqrtf(t), 1.0f), 0.0f);
                a[i] += (u * u) * (u * ndc);
            }
        };

        if (mp) {
            int k = __builtin_ctz(mp); mp &= mp - 1;
            int nk; float dqx, dqy, dqz;
            FETCH(k, nk, dqx, dqy, dqz);
            float ndc = data[(bN + nk) * CH + c];
            while (mp) {
                int k2 = __builtin_ctz(mp); mp &= mp - 1;
                int nk2; float dqx2, dqy2, dqz2;
                FETCH(k2, nk2, dqx2, dqy2, dqz2);
                float ndc2 = data[(bN + nk2) * CH + c];   // in flight during ACCUM
                ACCUM(acc[p], dqx, dqy, dqz, ndc);
                dqx = dqx2; dqy = dqy2; dqz = dqz2; ndc = ndc2;
            }
            ACCUM(acc[p], dqx, dqy, dqz, ndc);
        }
    }

    // ---- T14 write-late: stage weights to LDS (padded rows), then barrier ----
    #pragma unroll
    for (int j = 0; j < 4; ++j) {
        if (j < 3 || tid < 192) {
            float4 w = (j == 0) ? wr0 : (j == 1) ? wr1 : (j == 2) ? wr2 : wr3;
            int f  = (tid + j * 512) * 4;
            int r0 = (f + 0) / NCELL, e0 = (f + 0) - r0 * NCELL;
            int r1 = (f + 1) / NCELL, e1 = (f + 1) - r1 * NCELL;
            int r2 = (f + 2) / NCELL, e2 = (f + 2) - r2 * NCELL;
            int r3 = (f + 3) / NCELL, e3 = (f + 3) - r3 * NCELL;
            wlds[r0 * EPAD + e0] = w.x;
            wlds[r1 * EPAD + e1] = w.y;
            wlds[r2 * EPAD + e2] = w.z;
            wlds[r3 * EPAD + e3] = w.w;
        }
    }
    __syncthreads();

    // ---- contraction: weight reads shared across the wave's 4 points;
    //      butterfly on VALU (DPP/permlane) except xor4 ----
    float r0s = 0.f, r1s = 0.f, r2s = 0.f, r3s = 0.f;
    if (bl0 | bl1) {
        const float* wrow = &wlds[c * EPAD + h * 8];
        const int bit0 = c & 1;
        float vv[4][8];
        #pragma unroll
        for (int j = 0; j < 8; ++j) {
            const float4* wA = (const float4*)(wrow + (2 * j)     * CH * EPAD);
            const float4* wB = (const float4*)(wrow + (2 * j + 1) * CH * EPAD);
            float4 a0 = wA[0], a1 = wA[1];
            float4 b0 = wB[0], b1 = wB[1];
            #pragma unroll
            for (int p = 0; p < 4; ++p) {
                float pA = a0.x*acc[p][0] + a0.y*acc[p][1] + a0.z*acc[p][2] + a0.w*acc[p][3]
                         + a1.x*acc[p][4] + a1.y*acc[p][5] + a1.z*acc[p][6] + a1.w*acc[p][7];
                float pB = b0.x*acc[p][0] + b0.y*acc[p][1] + b0.z*acc[p][2] + b0.w*acc[p][3]
                         + b1.x*acc[p][4] + b1.y*acc[p][5] + b1.z*acc[p][6] + b1.w*acc[p][7];
                float keep = bit0 ? pB : pA;
                float send = bit0 ? pA : pB;
                vv[p][j] = keep + dpp_xor1(send);
            }
        }
        // stage 1: xor2 (DPP)
        {
            const int bit = (c >> 1) & 1;
            #pragma unroll
            for (int p = 0; p < 4; ++p)
                #pragma unroll
                for (int j = 0; j < 4; ++j) {
                    float keep = bit ? vv[p][2 * j + 1] : vv[p][2 * j];
                    float send = bit ? vv[p][2 * j]     : vv[p][2 * j + 1];
                    vv[p][j] = keep + dpp_xor2(send);
                }
        }
        // stage 2: xor4 (DS swizzle — no DPP pattern for lane^4)
        {
            const int bit = (c >> 2) & 1;
            #pragma unroll
            for (int p = 0; p < 4; ++p)
                #pragma unroll
                for (int j = 0; j < 2; ++j) {
                    float keep = bit ? vv[p][2 * j + 1] : vv[p][2 * j];
                    float send = bit ? vv[p][2 * j]     : vv[p][2 * j + 1];
                    vv[p][j] = keep + __shfl_xor(send, 4, 64);
                }
        }
        // stage 3: xor8 (DPP row_ror:8)
        {
            const int bit = (c >> 3) & 1;
            #pragma unroll
            for (int p = 0; p < 4; ++p) {
                float keep = bit ? vv[p][1] : vv[p][0];
                float send = bit ? vv[p][0] : vv[p][1];
                vv[p][0] = keep + dpp_xor8(send);
            }
        }
        // merge the 4 e-slices (h groups) per point: xor16, xor32 on VALU
        r0s = fold32(fold16(vv[0][0]));
        r1s = fold32(fold16(vv[1][0]));
        r2s = fold32(fold16(vv[2][0]));
        r3s = fold32(fold16(vv[3][0]));
    }

    // lane (c,h) writes point pt0+h, channel o=c -> out[pt0*16 + lane], 256B coalesced
    float rw = r0s;
    if (h == 1) rw = r1s;
    if (h == 2) rw = r2s;
    if (h == 3) rw = r3s;
    out[pt0 * CH + lane] = rw + bi;
}

extern "C" void kernel_launch(void* const* d_in, const int* in_sizes, int n_in,
                              void* d_out, int out_size, void* d_ws, size_t ws_size,
                              hipStream_t stream) {
    const float* qlocs     = (const float*)d_in[0];
    const float* locs      = (const float*)d_in[1];
    const float* data      = (const float*)d_in[2];
    const int*   neighbors = (const int*)d_in[3];
    const float* weight    = (const float*)d_in[4];
    const float* bias      = (const float*)d_in[5];
    float*       out       = (float*)d_out;

    const int BM = in_sizes[0] / 3;   // B*M = 16384
    dim3 grid(BM / 32), block(512);
    hipLaunchKernelGGL(convsp_kernel, grid, block, 0, stream,
                       qlocs, locs, data, neighbors, weight, bias, out);
}